// Round 8
// baseline (226.843 us; speedup 1.0000x reference)
//
#include <hip/hip_runtime.h>
#include <math.h>

#define T_LEN  176400
#define NHARM  64
#define NBANDS 65
#define NROWS  16
#define Q4     (T_LEN/4)   // 44100 float4 per row

// 2*pi*440 in f64 (bit-identical to Python's 2.0*np.pi*440.0).
static constexpr double PHCd = 2.0 * 3.14159265358979323846 * 440.0;
// f32 linspace step as jax computes it: fl32((4.0-0.0)/176399). Held as f64
// (exactly representable). i*DELTA32 is EXACT in f64 (18+24 < 53 mantissa bits),
// so fl32(i*DELTA32) replicates jax's f32 iota*delta bit-for-bit.
static constexpr double DELTA32 = (double)(float)(4.0 / 176399.0);
// Cody-Waite two-part 2*pi (HI has 25-bit mantissa; m*HI exact for m<=2^28).
static constexpr double TWOPI_HI = 0x1.921FB5p+2;
static constexpr double TWOPI_LO = 6.283185307179586476925287 - TWOPI_HI;
static constexpr double INV2PI   = 1.0 / 6.283185307179586476925287;

__global__ __launch_bounds__(256) void ddsp_main(
    const float* __restrict__ harm,    // [16][64]
    const float* __restrict__ nbands,  // [16][65]
    const float* __restrict__ adsr,    // [16][4]
    const float* __restrict__ gain,    // [16]
    const float* __restrict__ noise,   // [16][T]
    float* __restrict__ sig_out,       // [16][T] staging (d_out)
    unsigned int* __restrict__ rowmax) // [16] in ws, zeroed
{
    const int row = blockIdx.y;
    __shared__ float w[NHARM];
    if (threadIdx.x < NHARM) w[threadIdx.x] = harm[row*NHARM + threadIdx.x];
    __syncthreads();

    // ---- uniform per-row params (f32, matching the f32 jax pipeline) ----
    float nl = 0.0f;
    #pragma unroll
    for (int j = 0; j < NBANDS; ++j) nl += nbands[row*NBANDS + j];
    nl = (nl / (float)NBANDS) * 0.1f;   // mean * 0.1

    const float att = adsr[row*4+0], dcy = adsr[row*4+1],
                sus = adsr[row*4+2], rls = adsr[row*4+3];
    int a = (int)floorf(att*0.5f*44100.0f) + 1;
    int d = (int)floorf(dcy*0.5f*44100.0f) + 1;
    int r = (int)floorf(rls*0.5f*44100.0f) + 1;
    const int tot = a + d + r;
    if (tot > T_LEN) {   // dead for U[0,1] adsr, kept for parity
        const float sc = (float)T_LEN / (float)tot;
        a = (int)floorf((float)a*sc);
        d = (int)floorf((float)d*sc);
        r = (int)floorf((float)r*sc);
    }
    int slen = T_LEN - (a+d+r); if (slen < 0) slen = 0;
    const float a_f=(float)a, d_f=(float)d, r_f=(float)r, s_f=(float)slen;
    const float ad_f = a_f + d_f, ads_f = ad_f + s_f, adsr_f = ads_f + r_f;
    const float inv_a = 1.0f / fmaxf(a_f-1.0f, 1.0f);
    const float inv_d = 1.0f / fmaxf(d_f-1.0f, 1.0f);
    const float inv_r = 1.0f / fmaxf(r_f-1.0f, 1.0f);
    const float g = gain[row];

    float amax = 0.0f;
    const int i4 = blockIdx.x*256 + threadIdx.x;
    if (i4 < Q4) {
        const int i0 = i4*4;
        const float4 nz = *(const float4*)(noise + (size_t)row*T_LEN + i0);

        // per-sample rotation state (4 interleaved chains for ILP)
        float S[4], Cc[4], s1[4], c1[4], acc[4], t32[4];
        #pragma unroll
        for (int s2 = 0; s2 < 4; ++s2) {
            const int i = i0 + s2;
            const double td = (double)i * DELTA32;   // EXACT product in f64
            const float  tf = (float)td;             // == jax's f32 t, bit-exact
            t32[s2] = tf;
            // base angle alpha = PHCd * (exact value of t32), f64
            const double alpha = PHCd * (double)tf;
            // own range reduction (R7 proved == sincosf's, keep it: cheap+exact)
            const double m   = rint(alpha * INV2PI);
            const double rph = (alpha - m*TWOPI_HI) - m*TWOPI_LO;
            const float  th  = (float)rph;
            const float  tlo = (float)(rph - (double)th);
            float sn, cs;
            sincosf(th, &sn, &cs);
            const float sr = __builtin_fmaf(cs,  tlo, sn);
            const float cr = __builtin_fmaf(-sn, tlo, cs);
            s1[s2]=sr; c1[s2]=cr;       // rotation generator: angle alpha
            S[s2]=sr; Cc[s2]=cr;        // state = sin/cos(k*alpha), k=1
            acc[s2]=0.0f;
        }

        // REFERENCE (f32 jaxpr replica): phase pp = fl32(c_k * t32) in f32 with
        // c_k = fl32(PHCd*k); sin evaluated accurately at that f32 phase.
        // We replicate pp bit-exactly, recover D = pp - k*alpha exactly:
        //   r  = fma(ck,t32,-pp) = ck*t32 - pp          (exact, TwoProd)
        //   D  = e_k*t32 - r,  e_k = fl64(ck) - PHCd*k  (compile-time)
        // |D| <= ~0.063 rad; 3rd-order sin/cos correction (trunc <= 7e-7).
        #pragma unroll
        for (int k = 1; k <= NHARM; ++k) {
            const float ck = (float)(PHCd * (double)k);
            const float ek = (float)((double)ck - PHCd * (double)k);
            const float wk = w[k-1];
            #pragma unroll
            for (int s2 = 0; s2 < 4; ++s2) {
                const float pp  = ck * t32[s2];                         // ref phase bits
                const float rr  = __builtin_fmaf(ck, t32[s2], -pp);     // exact residual
                const float D   = __builtin_fmaf(ek, t32[s2], -rr);     // pp - k*alpha
                const float d2  = D * D;
                const float cA  = __builtin_fmaf(-0.5f, d2, 1.0f);          // cos D
                const float cB  = __builtin_fmaf(-0.16666667f, d2, 1.0f);
                const float DB  = D * cB;                                   // sin D
                const float val = __builtin_fmaf(Cc[s2], DB, S[s2]*cA);     // sin(kA+D)
                acc[s2] = __builtin_fmaf(wk, val, acc[s2]);
                // rotate by alpha: (S,C) <- (S*c1+C*s1, C*c1-S*s1)
                const float t1 = Cc[s2]*s1[s2];
                const float t2 = S[s2]*s1[s2];
                const float ns = __builtin_fmaf(S[s2],  c1[s2],  t1);
                const float nc = __builtin_fmaf(Cc[s2], c1[s2], -t2);
                S[s2]=ns; Cc[s2]=nc;
            }
        }

        float4 outv;
        #pragma unroll
        for (int s2 = 0; s2 < 4; ++s2) {
            const float i_f = (float)(i0 + s2);
            float env;
            if      (i_f < a_f)   env = (a_f > 1.0f) ? i_f * inv_a : 0.0f;
            else if (i_f < ad_f)  env = __builtin_fmaf((sus-1.0f)*(i_f-a_f), inv_d, 1.0f);
            else if (i_f < ads_f) env = sus;
            else if (i_f < adsr_f)env = sus * (1.0f - (i_f-ads_f)*inv_r);
            else                  env = 0.0f;
            const float nzv = (s2==0)?nz.x:(s2==1)?nz.y:(s2==2)?nz.z:nz.w;
            const float n   = (nzv*2.0f - 1.0f) * nl;
            const float sg  = ((acc[s2] + n) * env) * g;
            (&outv.x)[s2] = sg;
            amax = fmaxf(amax, fabsf(sg));
        }
        *(float4*)(sig_out + (size_t)row*T_LEN + i0) = outv;
    }

    // wave-level max reduce, then one device-scope atomic per wave
    #pragma unroll
    for (int off = 32; off > 0; off >>= 1)
        amax = fmaxf(amax, __shfl_xor(amax, off, 64));
    if ((threadIdx.x & 63) == 0)
        atomicMax(rowmax + row, __float_as_uint(amax));   // amax>=0: uint order == float order
}

__global__ __launch_bounds__(256) void ddsp_norm(
    float* __restrict__ sig, const unsigned int* __restrict__ rowmax)
{
    const int row = blockIdx.y;
    const int i4  = blockIdx.x*256 + threadIdx.x;
    if (i4 >= Q4) return;
    const float mv  = __uint_as_float(rowmax[row]) + 1e-5f;
    const float inv = 1.0f / mv;
    float4 v = *(float4*)(sig + (size_t)row*T_LEN + i4*4);
    v.x *= inv; v.y *= inv; v.z *= inv; v.w *= inv;
    *(float4*)(sig + (size_t)row*T_LEN + i4*4) = v;
}

extern "C" void kernel_launch(void* const* d_in, const int* in_sizes, int n_in,
                              void* d_out, int out_size, void* d_ws, size_t ws_size,
                              hipStream_t stream) {
    // inputs: 0=base_audio(unused) 1=harmonic_dist 2=noise_bands 3=adsr 4=gain 5=noise
    const float* harm  = (const float*)d_in[1];
    const float* nbp   = (const float*)d_in[2];
    const float* adsrp = (const float*)d_in[3];
    const float* gainp = (const float*)d_in[4];
    const float* noisp = (const float*)d_in[5];
    float* out = (float*)d_out;
    unsigned int* rowmax = (unsigned int*)d_ws;

    hipMemsetAsync(d_ws, 0, NROWS*sizeof(unsigned int), stream);
    dim3 grid((Q4 + 255)/256, NROWS);
    ddsp_main<<<grid, 256, 0, stream>>>(harm, nbp, adsrp, gainp, noisp, out, rowmax);
    ddsp_norm<<<grid, 256, 0, stream>>>(out, rowmax);
}

// Round 9
// 113.711 us; speedup vs baseline: 1.9949x; 1.9949x over previous
//
#include <hip/hip_runtime.h>
#include <math.h>

#define T_LEN  176400
#define NHARM  64
#define NBANDS 65
#define NROWS  16
#define Q4     (T_LEN/4)   // 44100 float4 per row

// 2*pi*440 in f64 (bit-identical to Python's 2.0*np.pi*440.0).
static constexpr double PHCd = 2.0 * 3.14159265358979323846 * 440.0;
// f32 linspace step as jax computes it: fl32((4.0-0.0)/176399), held in f64.
// i*DELTA32 is EXACT in f64 (18+24 < 53 mantissa bits).
static constexpr double DELTA32 = (double)(float)(4.0 / 176399.0);
// Cody-Waite two-part 2*pi (HI mantissa short enough that m*HI is exact).
static constexpr double TWOPI_HI = 0x1.921FB5p+2;
static constexpr double TWOPI_LO = 6.283185307179586476925287 - TWOPI_HI;
static constexpr double INV2PI   = 1.0 / 6.283185307179586476925287;

// t-major: one thread per sample t; 64 harmonic sins computed ONCE per t and
// shared across all 16 rows (was recomputed 16x in R8). Weights transposed
// into LDS, read as uniform b128 broadcasts (no conflicts). k-loop unroll 8
// (I$-resident body) with ck/ek from an LDS table.
__global__ __launch_bounds__(256) void ddsp_main(
    const float* __restrict__ harm,    // [16][64]
    const float* __restrict__ nbands,  // [16][65]
    const float* __restrict__ adsr,    // [16][4]
    const float* __restrict__ gain,    // [16]
    const float* __restrict__ noise,   // [16][T]
    float* __restrict__ sig_out,       // [16][T] staging (d_out)
    unsigned int* __restrict__ rowmax) // [16*16] in ws (64B-padded), zeroed
{
    __shared__ float4 wv[NHARM][4];    // wv[k][j] = w rows 4j..4j+3, harmonic k
    __shared__ float2 ckek[NHARM];     // {c_k, e_k}
    __shared__ float4 envA[NROWS];     // {a_f, ad_f, ads_f, adsr_f}
    __shared__ float4 envB[NROWS];     // {inv_a, inv_d, inv_r, sus}
    __shared__ float2 nlg[NROWS];      // {nl, g}
    __shared__ float  redbuf[4][NROWS];

    const int tid = threadIdx.x;

    // ---- ck/ek table (device f64, bit-identical to host constexpr math) ----
    if (tid < NHARM) {
        const double ckd = PHCd * (double)(tid + 1);
        const float ck = (float)ckd;
        const float ek = (float)((double)ck - ckd);
        ckek[tid] = make_float2(ck, ek);
    }
    // ---- transposed weights: linear idx = k*16 + r  <-  harm[r*64 + k] ----
    {
        float* wflat = (float*)wv;
        #pragma unroll
        for (int j = 0; j < 4; ++j) {
            const int idx = tid + 256*j;
            const int k = idx >> 4, r = idx & 15;
            wflat[idx] = harm[r*NHARM + k];
        }
    }
    // ---- per-row params (exact R8 f32 sequence) ----
    if (tid < NROWS) {
        const int row = tid;
        float nl = 0.0f;
        for (int j = 0; j < NBANDS; ++j) nl += nbands[row*NBANDS + j];
        nl = (nl / (float)NBANDS) * 0.1f;
        const float att = adsr[row*4+0], dcy = adsr[row*4+1],
                    sus = adsr[row*4+2], rls = adsr[row*4+3];
        int a = (int)floorf(att*0.5f*44100.0f) + 1;
        int d = (int)floorf(dcy*0.5f*44100.0f) + 1;
        int r = (int)floorf(rls*0.5f*44100.0f) + 1;
        const int tot = a + d + r;
        if (tot > T_LEN) {   // dead for U[0,1] adsr, kept for parity
            const float sc = (float)T_LEN / (float)tot;
            a = (int)floorf((float)a*sc);
            d = (int)floorf((float)d*sc);
            r = (int)floorf((float)r*sc);
        }
        int slen = T_LEN - (a+d+r); if (slen < 0) slen = 0;
        const float a_f=(float)a, d_f=(float)d, r_f=(float)r, s_f=(float)slen;
        const float ad_f = a_f + d_f;            // same assoc as R8
        const float ads_f = ad_f + s_f;
        const float adsr_f = ads_f + r_f;
        envA[row] = make_float4(a_f, ad_f, ads_f, adsr_f);
        envB[row] = make_float4(1.0f/fmaxf(a_f-1.0f,1.0f),
                                1.0f/fmaxf(d_f-1.0f,1.0f),
                                1.0f/fmaxf(r_f-1.0f,1.0f), sus);
        nlg[row]  = make_float2(nl, gain[row]);
    }
    __syncthreads();

    const int t = blockIdx.x*256 + tid;
    const bool act = (t < T_LEN);

    // ---- seed: sin/cos(alpha), alpha = PHCd * (f64 of f32 t)  [== R8] ----
    const double td = (double)t * DELTA32;   // exact in f64
    const float  tf = (float)td;             // jax's f32 t, bit-exact
    const double alpha = PHCd * (double)tf;
    const double mq  = rint(alpha * INV2PI);
    const double rph = (alpha - mq*TWOPI_HI) - mq*TWOPI_LO;
    const float  th  = (float)rph;
    const float  tlo = (float)(rph - (double)th);
    float sn, cs;
    sincosf(th, &sn, &cs);
    const float s1 = __builtin_fmaf(cs,  tlo, sn);
    const float c1 = __builtin_fmaf(-sn, tlo, cs);
    float S = s1, Cc = c1;

    float acc[NROWS];
    #pragma unroll
    for (int r = 0; r < NROWS; ++r) acc[r] = 0.0f;

    // ---- k-loop: sin once per (k,t), 16 row-FMAs share it ----
    #pragma unroll 8
    for (int k = 0; k < NHARM; ++k) {
        const float2 ce = ckek[k];
        const float4 w0 = wv[k][0];
        const float4 w1 = wv[k][1];
        const float4 w2 = wv[k][2];
        const float4 w3 = wv[k][3];
        // ref phase pp = fl32(c_k * t32); D = pp - k*alpha (exact recovery)
        const float pp = ce.x * tf;
        const float rr = __builtin_fmaf(ce.x, tf, -pp);
        const float D  = __builtin_fmaf(ce.y, tf, -rr);
        const float d2 = D * D;
        const float cA = __builtin_fmaf(-0.5f, d2, 1.0f);
        const float cB = __builtin_fmaf(-0.16666667f, d2, 1.0f);
        const float DB = D * cB;
        const float val = __builtin_fmaf(Cc, DB, S*cA);   // sin(kA + D)
        acc[ 0] = __builtin_fmaf(w0.x, val, acc[ 0]);
        acc[ 1] = __builtin_fmaf(w0.y, val, acc[ 1]);
        acc[ 2] = __builtin_fmaf(w0.z, val, acc[ 2]);
        acc[ 3] = __builtin_fmaf(w0.w, val, acc[ 3]);
        acc[ 4] = __builtin_fmaf(w1.x, val, acc[ 4]);
        acc[ 5] = __builtin_fmaf(w1.y, val, acc[ 5]);
        acc[ 6] = __builtin_fmaf(w1.z, val, acc[ 6]);
        acc[ 7] = __builtin_fmaf(w1.w, val, acc[ 7]);
        acc[ 8] = __builtin_fmaf(w2.x, val, acc[ 8]);
        acc[ 9] = __builtin_fmaf(w2.y, val, acc[ 9]);
        acc[10] = __builtin_fmaf(w2.z, val, acc[10]);
        acc[11] = __builtin_fmaf(w2.w, val, acc[11]);
        acc[12] = __builtin_fmaf(w3.x, val, acc[12]);
        acc[13] = __builtin_fmaf(w3.y, val, acc[13]);
        acc[14] = __builtin_fmaf(w3.z, val, acc[14]);
        acc[15] = __builtin_fmaf(w3.w, val, acc[15]);
        // rotate by alpha (same op order as R8)
        const float t1 = Cc * s1;
        const float t2 = S  * s1;
        const float ns = __builtin_fmaf(S,  c1,  t1);
        const float nc = __builtin_fmaf(Cc, c1, -t2);
        S = ns; Cc = nc;
    }

    // ---- epilogue: 16 rows at this t ----
    float amr[NROWS];
    const float i_f = (float)t;
    #pragma unroll
    for (int r = 0; r < NROWS; ++r) {
        float am = 0.0f;
        if (act) {
            const float  nz = noise[(size_t)r*T_LEN + t];
            const float4 eA = envA[r];
            const float4 eB = envB[r];
            const float2 ng = nlg[r];
            float env;
            if      (i_f < eA.x) env = (eA.x > 1.0f) ? i_f * eB.x : 0.0f;
            else if (i_f < eA.y) env = __builtin_fmaf((eB.w-1.0f)*(i_f-eA.x), eB.y, 1.0f);
            else if (i_f < eA.z) env = eB.w;
            else if (i_f < eA.w) env = eB.w * (1.0f - (i_f-eA.z)*eB.z);
            else                 env = 0.0f;
            const float n  = (nz*2.0f - 1.0f) * ng.x;
            const float sg = ((acc[r] + n) * env) * ng.y;
            sig_out[(size_t)r*T_LEN + t] = sg;
            am = fabsf(sg);
        }
        amr[r] = am;
    }

    // ---- per-row wave max-reduce (16 interleaved butterflies) ----
    #pragma unroll
    for (int off = 32; off > 0; off >>= 1) {
        #pragma unroll
        for (int r = 0; r < NROWS; ++r)
            amr[r] = fmaxf(amr[r], __shfl_xor(amr[r], off, 64));
    }
    if ((tid & 63) == 0) {
        const int wid = tid >> 6;
        #pragma unroll
        for (int r = 0; r < NROWS; ++r) redbuf[wid][r] = amr[r];
    }
    __syncthreads();
    if (tid < NROWS) {
        const float m01 = fmaxf(redbuf[0][tid], redbuf[1][tid]);
        const float m23 = fmaxf(redbuf[2][tid], redbuf[3][tid]);
        atomicMax(rowmax + tid*16, __float_as_uint(fmaxf(m01, m23)));
    }
}

__global__ __launch_bounds__(256) void ddsp_norm(
    float* __restrict__ sig, const unsigned int* __restrict__ rowmax)
{
    const int row = blockIdx.y;
    const int i4  = blockIdx.x*256 + threadIdx.x;
    if (i4 >= Q4) return;
    const float mv  = __uint_as_float(rowmax[row*16]) + 1e-5f;
    const float inv = 1.0f / mv;
    float4 v = *(float4*)(sig + (size_t)row*T_LEN + i4*4);
    v.x *= inv; v.y *= inv; v.z *= inv; v.w *= inv;
    *(float4*)(sig + (size_t)row*T_LEN + i4*4) = v;
}

extern "C" void kernel_launch(void* const* d_in, const int* in_sizes, int n_in,
                              void* d_out, int out_size, void* d_ws, size_t ws_size,
                              hipStream_t stream) {
    // inputs: 0=base_audio(unused) 1=harmonic_dist 2=noise_bands 3=adsr 4=gain 5=noise
    const float* harm  = (const float*)d_in[1];
    const float* nbp   = (const float*)d_in[2];
    const float* adsrp = (const float*)d_in[3];
    const float* gainp = (const float*)d_in[4];
    const float* noisp = (const float*)d_in[5];
    float* out = (float*)d_out;
    unsigned int* rowmax = (unsigned int*)d_ws;   // 16 counters, 64B-padded

    hipMemsetAsync(d_ws, 0, NROWS*16*sizeof(unsigned int), stream);
    ddsp_main<<<dim3((T_LEN + 255)/256), 256, 0, stream>>>(
        harm, nbp, adsrp, gainp, noisp, out, rowmax);
    ddsp_norm<<<dim3((Q4 + 255)/256, NROWS), 256, 0, stream>>>(out, rowmax);
}